// Round 8
// baseline (139.293 us; speedup 1.0000x reference)
//
#include <hip/hip_runtime.h>
#include <cmath>
#include <algorithm>
#include <cstdint>

#ifndef M_PI
#define M_PI 3.14159265358979323846
#endif

// Problem constants (fixed by setup_inputs in the reference)
#define B_ 8
#define F_ 3
#define H_ 224
#define W_ 224
#define T_ 8          // ntau
#define A_ 12         // num_angles
#define NK 96         // T_*A_
#define HS_ 112
#define WS_ 112
#define PLANE_ (H_ * W_)        // 50176
#define SLICE_ (HS_ * WS_)      // 12544

// R8: fill-shaped main kernel (no LDS, no barriers, 256-thread blocks)
// gathering from the 4-phase permuted copy P (R7's pre-pass, proven correct).
// Evidence: six LDS-variant levers all pinned at ~35 us; per-pipe models sum
// to ~20-24. Shared residue of all ~35 us variants: 1024-thread barrier-
// synced blocks + 672-block coarse grid + serial stage->compute phases.
// The 6.6 TB/s fill has none of those. P makes every tap a lane-stride-1
// dword gather (fixes R3's stride-2 / 50%-line-waste / 4x-instr failure):
//   inp[bfr][c] == P[bfr][(c&3)*56 + (c>>2)],  c = 4l + (cx+t), s=cx+t uniform
//   -> phase s&3 uniform, index l + (s>>2) dense across 56 lanes (224 B span).
// Block = (bf, k, 16 rows): 8 loads + 16 FMA + 1 dwordx2 store per row,
// 7 KB dense store region per block; grid 16128 = 8 XCD x 2016 (bijective
// swizzle -> 3 bf-planes/XCD, P reads L2-resident); 8 blocks/CU, no tail.

struct LPNat {            // natural k order (main kernel)
    int   cy[NK];  int cx[NK];
    float fy[NK];  float fx[NK];
};
struct LPSort {           // cy-sorted groups (fallback kernel, R6 verbatim)
    int   cy[NK];  int cx[NK];
    float fy[NK];  float fx[NK];
    int   korig[NK];
    int   cymin[2]; int cymax[2];
};

static void host_consts(int* cy, int* cx, float* fy, float* fx) {
    double c = pow(60.0, 1.0 / 7.0) - 1.0;
    for (int t = 0; t < T_; ++t) {
        double tau = pow(1.0 + c, (double)t);
        for (int a = 0; a < A_; ++a) {
            double th = (double)a * (2.0 * M_PI / (double)A_) - M_PI;
            float yo = (float)(tau * sin(th)), xo = (float)(tau * cos(th));
            int k = t * A_ + a;
            float yf = floorf(yo), xf = floorf(xo);
            cy[k] = (int)yf; fy[k] = yo - yf;
            cx[k] = (int)xf; fx[k] = xo - xf;
        }
    }
}

static LPNat make_nat() {
    LPNat r;
    host_consts(r.cy, r.cx, r.fy, r.fx);
    return r;
}

static LPSort make_sort() {
    int cy[NK], cx[NK]; float fy[NK], fx[NK];
    host_consts(cy, cx, fy, fx);
    int idx[NK];
    for (int k = 0; k < NK; ++k) idx[k] = k;
    std::sort(idx, idx + NK, [&](int a, int b) { return cy[a] < cy[b]; });
    LPSort r;
    r.cymin[0] = r.cymin[1] = 1000; r.cymax[0] = r.cymax[1] = -1000;
    for (int p = 0; p < NK; ++p) {
        int k = idx[p], g = p / 48;
        r.cy[p] = cy[k]; r.cx[p] = cx[k];
        r.fy[p] = fy[k]; r.fx[p] = fx[k];
        r.korig[p] = k;
        r.cymin[g] = std::min(r.cymin[g], cy[k]);
        r.cymax[g] = std::max(r.cymax[g], cy[k]);
    }
    return r;
}

#define PH4 56        // phase length (dwords)
#define PITCH4 224    // P row pitch = 4*PH4

// ---- pre-pass: permute input into 4-phase layout in workspace (R7, proven) ----
__global__ __launch_bounds__(256) void lp_permute_kernel(
    const float* __restrict__ inp, float* __restrict__ P) {
    const int q = (int)blockIdx.x * 256 + (int)threadIdx.x;  // 0..301055
    const float4 v = ((const float4*)inp)[q];
    const int bfr = q / PH4;             // global plane-row index (24*224)
    const int u   = q - bfr * PH4;
    float* row = P + (size_t)bfr * PITCH4;
    row[u]           = v.x;   // col 4u   (phase 0)
    row[PH4 + u]     = v.y;   // col 4u+1 (phase 1)
    row[2 * PH4 + u] = v.z;   // col 4u+2 (phase 2)
    row[3 * PH4 + u] = v.w;   // col 4u+3 (phase 3)
}

// ---- main: barrier-free P-gather, 256 threads, 16 rows of one (bf,k) ----
__global__ __launch_bounds__(256, 8) void lp_pg_kernel(
    const float* __restrict__ P, float* __restrict__ out, LPNat args) {

    const int blk = (int)blockIdx.x;               // 0..16127
    const int swz = (blk & 7) * 2016 + (blk >> 3); // bijective (16128 = 8*2016)
    const int bf  = swz / 672;                     // 0..23
    const int rem = swz - bf * 672;
    const int k   = rem / 7;                       // 0..95 (t*A + a, natural)
    const int ib  = rem - k * 7;                   // 0..6
    const int i0  = ib * 16;

    const int lane = (int)threadIdx.x & 63;
    const int wave = (int)threadIdx.x >> 6;        // 0..3

    const int   cy = args.cy[k]; const float fy = args.fy[k];
    const int   cx = args.cx[k]; const float fx = args.fx[k];
    const float omfx = 1.0f - fx;

    const float* Pp = P + (size_t)bf * PLANE_;

    // per-lane tap offsets + weights, once per block (cx uniform):
    // lane l -> out cols {2l, 2l+1}; tap t -> input col 4l + s, s = cx+t.
    const int l = lane;
    int   off[4]; float tw[4];
#pragma unroll
    for (int t = 0; t < 4; ++t) {
        const int s  = cx + t;                     // uniform
        const int ct = 4 * l + s;                  // tap column
        int u = l + (s >> 2);                      // exact: (4l+s)>>2
        u = min(max(u, 0), PH4 - 1);               // weight is 0 when clamped
        off[t] = (s & 3) * PH4 + u;                // dense lane-stride-1
        tw[t]  = (ct >= 0 && ct < W_) ? ((t & 1) ? fx : omfx) : 0.0f;
    }

    const bool act = (l < PH4);                    // 56 active lanes
    float* obase = out + ((size_t)bf * NK + k) * SLICE_
                       + (size_t)i0 * WS_ + 2 * l;

#pragma unroll
    for (int r = 0; r < 4; ++r) {
        const int di  = wave + 4 * r;              // rows 0..15, block-dense
        const int iy0 = 2 * (i0 + di) + cy;        // wave-uniform
        float mA, mB;                              // slot-shifting clamp scheme
        if (iy0 >= 0 && iy0 <= H_ - 2)  { mA = 1.0f - fy; mB = fy; }
        else if (iy0 == -1)             { mA = fy;        mB = 0.0f; }
        else if (iy0 == H_ - 1)         { mA = 0.0f;      mB = 1.0f - fy; }
        else                            { mA = 0.0f;      mB = 0.0f; }
        const int by = min(max(iy0, 0), H_ - 2);   // rows {by, by+1}

        const float* pa = Pp + (size_t)by * PITCH4;
        const float* pb = pa + PITCH4;
        // 8 dword gathers, each 56 lanes dense over 224 B (2 cache lines)
        const float a0 = pa[off[0]], b0 = pa[off[1]];
        const float c0 = pa[off[2]], d0 = pa[off[3]];
        const float a1 = pb[off[0]], b1 = pb[off[1]];
        const float c1 = pb[off[2]], d1 = pb[off[3]];

        float2 rr;
        rr.x = mA * (tw[0] * a0 + tw[1] * b0) + mB * (tw[0] * a1 + tw[1] * b1);
        rr.y = mA * (tw[2] * c0 + tw[3] * d0) + mB * (tw[2] * c1 + tw[3] * d1);

        if (act) *(float2*)(obase + (size_t)di * WS_) = rr;   // dwordx2
    }
}

// ---- fallback: R6 verbatim (measured 35.5 us), used if ws too small ----
#define RI 8
#define BANDROWS 78
#define FPH 57
#define FPITCH 228
#define NLANE 56
__global__ __launch_bounds__(1024, 8) void lp_fallback_kernel(
    const float* __restrict__ inp, float* __restrict__ out, LPSort args) {

    __shared__ float lds[BANDROWS * FPITCH];

    const int bf = blockIdx.x;
    const int i0 = blockIdx.y * RI;
    const int g  = blockIdx.z;

    const int r0 = max(0, 2 * i0 + args.cymin[g]);
    const int r1 = min(H_ - 1, 2 * i0 + 2 * (RI - 1) + args.cymax[g] + 1);
    const int nrows = min(r1 - r0 + 1, BANDROWS);

    const float* plane = inp + (size_t)bf * PLANE_;
    {
        const int n = nrows * (W_ / 4);
        for (int v = threadIdx.x; v < n; v += 1024) {
            const unsigned r = (unsigned)v / 56u;
            const int u = v - (int)r * 56;
            const float4 val = *(const float4*)(plane + (size_t)(r0 + (int)r) * W_ + 4 * u);
            float* rowp = lds + r * FPITCH + u;
            rowp[0 * FPH] = val.x; rowp[1 * FPH] = val.y;
            rowp[2 * FPH] = val.z; rowp[3 * FPH] = val.w;
        }
    }
    __syncthreads();

    const int lane = threadIdx.x & 63;
    const int wave = __builtin_amdgcn_readfirstlane((int)threadIdx.x >> 6);
    float* outp = out + (size_t)bf * (NK * SLICE_) + (size_t)i0 * WS_;
    const bool act = (lane < NLANE);

#pragma unroll 1
    for (int tt = 0; tt < 3; ++tt) {
        const int kk = g * 48 + wave + (tt << 4);
        const int   cy = args.cy[kk]; const float fy = args.fy[kk];
        const int   cx = args.cx[kk]; const float fx = args.fx[kk];
        const int   ko = args.korig[kk];
        const float omfx = 1.0f - fx;
        const int l = lane;
        const float* tp[4]; float tw[4];
#pragma unroll
        for (int t = 0; t < 4; ++t) {
            const int s = cx + t; const int ct = 4 * l + s; const int ph = s & 3;
            int idx = l + (s >> 2);
            idx = min(max(idx, 0), NLANE - 1);
            tp[t] = lds + ph * FPH + idx;
            tw[t] = (ct >= 0 && ct < W_) ? ((t & 1) ? fx : omfx) : 0.0f;
        }
        float2* orow = (float2*)(outp + (size_t)ko * SLICE_) + l;
        if (act) {
#pragma unroll 2
            for (int di = 0; di < RI; ++di) {
                const int iy0 = 2 * (i0 + di) + cy;
                float mA, mB;
                if (iy0 >= 0 && iy0 <= H_ - 2)  { mA = 1.0f - fy; mB = fy; }
                else if (iy0 == -1)             { mA = fy;        mB = 0.0f; }
                else if (iy0 == H_ - 1)         { mA = 0.0f;      mB = 1.0f - fy; }
                else                            { mA = 0.0f;      mB = 0.0f; }
                const int by = min(max(iy0, 0), H_ - 2);
                const int rb = min(by - r0, BANDROWS - 2) * FPITCH;
                const float a0 = tp[0][rb], a1 = tp[0][rb + FPITCH];
                const float b0 = tp[1][rb], b1 = tp[1][rb + FPITCH];
                const float c0 = tp[2][rb], c1 = tp[2][rb + FPITCH];
                const float d0 = tp[3][rb], d1 = tp[3][rb + FPITCH];
                float2 rr;
                rr.x = mA * (tw[0] * a0 + tw[1] * b0) + mB * (tw[0] * a1 + tw[1] * b1);
                rr.y = mA * (tw[2] * c0 + tw[3] * d0) + mB * (tw[2] * c1 + tw[3] * d1);
                orow[(size_t)di * (WS_ / 2)] = rr;
            }
        }
    }
}

extern "C" void kernel_launch(void* const* d_in, const int* in_sizes, int n_in,
                              void* d_out, int out_size, void* d_ws, size_t ws_size,
                              hipStream_t stream) {
    const float* inp = (const float*)d_in[0];
    float*       out = (float*)d_out;

    const size_t needP = (size_t)B_ * F_ * PLANE_ * sizeof(float);  // 4.82 MB
    if (d_ws != nullptr && ws_size >= needP) {
        static const LPNat nat = make_nat();      // host-side, once
        float* P = (float*)d_ws;
        lp_permute_kernel<<<dim3((B_ * F_ * PLANE_ / 4) / 256), 256, 0, stream>>>(inp, P);
        lp_pg_kernel<<<dim3(24 * 96 * 7), 256, 0, stream>>>(P, out, nat);
    } else {
        static const LPSort srt = make_sort();
        lp_fallback_kernel<<<dim3(B_ * F_, HS_ / RI, 2), 1024, 0, stream>>>(inp, out, srt);
    }
}

// Round 9
// 137.803 us; speedup vs baseline: 1.0108x; 1.0108x over previous
//
#include <hip/hip_runtime.h>
#include <cmath>
#include <algorithm>

#ifndef M_PI
#define M_PI 3.14159265358979323846
#endif

// Problem constants (fixed by setup_inputs in the reference)
#define B_ 8
#define F_ 3
#define H_ 224
#define W_ 224
#define T_ 8          // ntau
#define A_ 12         // num_angles
#define NK 96         // T_*A_
#define STRIDE_ 2
#define HS_ 112
#define WS_ 112
#define PLANE_ (H_ * W_)        // 50176
#define SLICE_ (HS_ * WS_)      // 12544

// R9 = revert to R2, the best harness-verified kernel (133.295 us).
// Session conclusion (7 structures, R0-R8): kernel portion is pinned at
// ~35 us regardless of bank conflicts, staging volume, store contiguity/
// width, wave-iter count, ds_write count, barriers, or grid shape.
// Model: 115.6 MB store stream (~17.5 us at fill-rate 6.6 TB/s) +
// per-dispatch ramp/launch (~15 us) + fixed ~98.4 us harness portion
// (poison fill 69.5 us + gaps). This variant: single dispatch,
// conflict-free deinterleaved LDS, no workspace dependency.
#define RI 8          // output rows per block
#define BANDROWS 78   // 2*(RI-1) + group cy-range (59) + 2 = 75 max (<=78)
#define PITCH 225     // LDS row pitch in dwords: E[0..111] | O[0..111] | 1 pad
#define HALF 112

// Per-offset constants (host, f64) reordered into two cy-sorted groups of 48
// so each group's row-band fits 70.2 KB LDS -> 2 blocks/CU. korig maps back
// to output k = t*A + a. Group 0 = negative cy (-60..-1), group 1 = 0..59.
// Per-offset (vs per-element f32) floor/frac is continuity-safe: validated
// across rounds, absmax 1.5625e-2 << tolerance.
struct LPArgs {
    int   cy[NK];  int cx[NK];
    float fy[NK];  float fx[NK];
    int   korig[NK];
    int   cymin[2]; int cymax[2];
};

static LPArgs make_args() {
    int cy[NK], cx[NK]; float fy[NK], fx[NK];
    double c = pow(60.0, 1.0 / 7.0) - 1.0;
    for (int t = 0; t < T_; ++t) {
        double tau = pow(1.0 + c, (double)t);
        for (int a = 0; a < A_; ++a) {
            double th = (double)a * (2.0 * M_PI / (double)A_) - M_PI;
            float yo = (float)(tau * sin(th)), xo = (float)(tau * cos(th));
            int k = t * A_ + a;
            float yf = floorf(yo), xf = floorf(xo);
            cy[k] = (int)yf; fy[k] = yo - yf;
            cx[k] = (int)xf; fx[k] = xo - xf;
        }
    }
    int idx[NK];
    for (int k = 0; k < NK; ++k) idx[k] = k;
    std::sort(idx, idx + NK, [&](int a, int b) { return cy[a] < cy[b]; });
    LPArgs r;
    r.cymin[0] = r.cymin[1] = 1000; r.cymax[0] = r.cymax[1] = -1000;
    for (int p = 0; p < NK; ++p) {
        int k = idx[p], g = p / 48;
        r.cy[p] = cy[k]; r.cx[p] = cx[k];
        r.fy[p] = fy[k]; r.fx[p] = fx[k];
        r.korig[p] = k;
        r.cymin[g] = std::min(r.cymin[g], cy[k]);
        r.cymax[g] = std::max(r.cymax[g], cy[k]);
    }
    return r;
}

// Grid (24 planes, 14 i-tiles, 2 cy-groups), block 1024 (16 waves),
// LDS 70.2 KB, launch_bounds(1024,8) forces VGPR<=64 -> 2 blocks/CU.
//
// LDS layout is even/odd-column DEINTERLEAVED per row (pitch 225 dwords):
//   row r: [E[c]=inp[r][2c] c=0..111 | O[c]=inp[r][2c+1] | pad]
// A bilinear x-pair {ix0, ix0+1} is always one even + one odd column, so
// each lane reads E and O at lane-stride-1 -> zero bank conflicts;
// ds_read2_b32 offset1:225 fetches both y-rows of each array in one instr.
__global__ __launch_bounds__(1024, 8) void lp_sample_kernel(
    const float* __restrict__ inp, float* __restrict__ out, LPArgs args) {

    __shared__ float lds[BANDROWS * PITCH];   // 78*225*4 = 70,200 B

    const int bf = blockIdx.x;            // b*F + f
    const int i0 = blockIdx.y * RI;
    const int g  = blockIdx.z;

    const int r0 = max(0, 2 * i0 + args.cymin[g]);
    const int r1 = min(H_ - 1, 2 * i0 + 2 * (RI - 1) + args.cymax[g] + 1);
    const int nrows = min(r1 - r0 + 1, BANDROWS);   // defensive clamp

    const float* plane = inp + (size_t)bf * PLANE_;

    {   // staging with even/odd deinterleave: float4 {e,o,e,o} -> E-pair + O-pair
        const int n = nrows * (W_ / 4);   // <= 78*56 = 4368
        for (int v = threadIdx.x; v < n; v += 1024) {
            const unsigned r = (unsigned)v / 56u;       // compiler magic-div
            const int u = v - (int)r * 56;              // float4 index in row
            const float4 val = *(const float4*)(plane + (size_t)(r0 + (int)r) * W_ + 4 * u);
            float* rowp = lds + r * PITCH;
            const int e = 2 * u;
            rowp[e]            = val.x;   // col 4u   (even)
            rowp[e + 1]        = val.z;   // col 4u+2 (even)
            rowp[HALF + e]     = val.y;   // col 4u+1 (odd)
            rowp[HALF + e + 1] = val.w;   // col 4u+3 (odd)
        }
    }
    __syncthreads();

    const int lane = threadIdx.x & 63;
    const int wave = __builtin_amdgcn_readfirstlane((int)threadIdx.x >> 6);

    float* outp = out + (size_t)bf * (NK * SLICE_) + (size_t)i0 * WS_;

#pragma unroll 1
    for (int tt = 0; tt < 6; ++tt) {
        const int task = wave + (tt << 4);            // 0..95
        const int kl   = task >> 1;                   // 0..47 within group
        const int h    = task & 1;                    // column half
        const int kk   = g * 48 + kl;

        const int   cy = args.cy[kk]; const float fy = args.fy[kk];
        const int   cx = args.cx[kk]; const float fx = args.fx[kk];
        const int   ko = args.korig[kk];
        const int   P  = cx & 1;                      // x-pair parity (uniform)

        // --- per-task x-side setup (amortized over RI=8 rows) ---
        const int j   = h * 64 + lane;
        const int ix0 = 2 * j + cx;                   // true left column
        const float wLv = (ix0 >= 0  && ix0 <= W_ - 1) ? (1.0f - fx) : 0.0f;
        const float wRv = (ix0 >= -1 && ix0 <= W_ - 2) ? fx          : 0.0f;
        // even col = ix0+P, odd col = ix0+1-P (ix0 parity == P per lane)
        int eidx = (ix0 + P) >> 1;                    // arith shift; clamp below
        int oidx = (ix0 + 1 - P) >> 1;
        eidx = min(max(eidx, 0), HALF - 1);           // weights are 0 when clamped
        oidx = min(max(oidx, 0), HALF - 1);
        const float wE = P ? wRv : wLv;               // uniform select
        const float wO = P ? wLv : wRv;

        const float* eptr = lds + eidx;               // lane-stride-1 -> no conflicts
        const float* optr = lds + HALF + oidx;

        float* orow = outp + (size_t)ko * SLICE_ + j;

        if (j < WS_) {                                // mask idle lanes for whole loop
#pragma unroll 2
            for (int di = 0; di < RI; ++di) {
                const int iy0 = 2 * (i0 + di) + cy;   // wave-uniform
                float mA, mB;
                if (iy0 >= 0 && iy0 <= H_ - 2)  { mA = 1.0f - fy; mB = fy; }
                else if (iy0 == -1)             { mA = fy;        mB = 0.0f; }
                else if (iy0 == H_ - 1)         { mA = 0.0f;      mB = 1.0f - fy; }
                else                            { mA = 0.0f;      mB = 0.0f; }
                const int by = min(max(iy0, 0), H_ - 2);  // rows {by,by+1} staged
                const int rb = min(by - r0, BANDROWS - 2) * PITCH;  // uniform

                // ds_read2_b32 offset0:0 offset1:225 x2 (conflict-free)
                const float e0 = eptr[rb], e1 = eptr[rb + PITCH];
                const float o0 = optr[rb], o1 = optr[rb + PITCH];

                const float rr = wE * (mA * e0 + mB * e1)
                               + wO * (mA * o0 + mB * o1);

                orow[(size_t)di * WS_] = rr;          // imm offset di*448
            }
        }
    }
}

extern "C" void kernel_launch(void* const* d_in, const int* in_sizes, int n_in,
                              void* d_out, int out_size, void* d_ws, size_t ws_size,
                              hipStream_t stream) {
    const float* inp = (const float*)d_in[0];
    float*       out = (float*)d_out;

    static const LPArgs args = make_args();   // host-side, once; capture-safe

    dim3 grid(B_ * F_, HS_ / RI, 2);          // 24 x 14 x 2
    lp_sample_kernel<<<grid, 1024, 0, stream>>>(inp, out, args);
}